// Round 14
// baseline (63.945 us; speedup 1.0000x reference)
//
#include <hip/hip_runtime.h>
#include <math.h>

typedef float v2f __attribute__((ext_vector_type(2)));

#define N_POINTS 32768
#define NUM_EMBED 8192
#define NPAIRS 4096
#define CH 64                                // chunks (64 chunk-mins fit one wave)
#define CPC (NUM_EMBED / CH)                 // 128 candidates per chunk
#define PAIRS (NPAIRS / CH)                  // 64 pairs per chunk (1 per lane in resolve)
#define PPT 8                                // filter points per thread
#define RB 512                               // resolve block threads (8 waves, 8 points)
#define CSTRIDE 4096                         // 64*64, channel stride in z [B,C,H,W]

// ---------------- kernel A: build pair-interleaved codebook + ee (exact XLA arithmetic)
__global__ void vq_prep_kernel(const float4* __restrict__ E,
                               v2f* __restrict__ Epk, v2f* __restrict__ eev) {
    int p = blockIdx.x * 256 + threadIdx.x;
    if (p < NPAIRS) {
        float4 a = E[2 * p];
        float4 b = E[2 * p + 1];
        Epk[4 * p + 0] = (v2f){a.x, b.x};
        Epk[4 * p + 1] = (v2f){a.y, b.y};
        Epk[4 * p + 2] = (v2f){a.z, b.z};
        Epk[4 * p + 3] = (v2f){a.w, b.w};
        float ea = __fmul_rn(a.x, a.x);
        ea = __fadd_rn(ea, __fmul_rn(a.y, a.y));
        ea = __fadd_rn(ea, __fmul_rn(a.z, a.z));
        ea = __fadd_rn(ea, __fmul_rn(a.w, a.w));
        float eb = __fmul_rn(b.x, b.x);
        eb = __fadd_rn(eb, __fmul_rn(b.y, b.y));
        eb = __fadd_rn(eb, __fmul_rn(b.z, b.z));
        eb = __fadd_rn(eb, __fmul_rn(b.w, b.w));
        eev[p] = (v2f){ea, eb};
    }
}

// packed f32 ops forced via inline asm (per-half IEEE rn; deterministic)
__device__ __forceinline__ v2f pk_add(v2f a, v2f b) {
    v2f d; asm("v_pk_add_f32 %0, %1, %2" : "=v"(d) : "v"(a), "v"(b)); return d;
}
__device__ __forceinline__ v2f pk_mul(v2f a, v2f b) {
    v2f d; asm("v_pk_mul_f32 %0, %1, %2" : "=v"(d) : "v"(a), "v"(b)); return d;
}
__device__ __forceinline__ v2f pk_fma(v2f a, v2f b, v2f c) {
    v2f d; asm("v_pk_fma_f32 %0, %1, %2, %3" : "=v"(d) : "v"(a), "v"(b), "v"(c)); return d;
}

// ---------------- kernel B (filter): per (point, chunk) EXACT min of d (value only)
// d chain = the proven bit-exact reference chain (r8): szz=zz+ee; mul+fma dot; fma(-2,...)
__global__ __launch_bounds__(256, 1) void vq_filter_kernel(
        const float* __restrict__ z, const v2f* __restrict__ Epk,
        const v2f* __restrict__ eev, float* __restrict__ dmin) {
    __shared__ alignas(16) v2f sE[PAIRS * 4];   // 2 KB
    __shared__ alignas(16) v2f see[PAIRS];      // 512 B

    const int c = blockIdx.y;
    {
        const float4* gE = (const float4*)(Epk + (size_t)c * PAIRS * 4);
        if (threadIdx.x < PAIRS * 2) {
            ((float4*)sE)[threadIdx.x] = gE[threadIdx.x];
        } else if (threadIdx.x < PAIRS * 2 + PAIRS / 2) {
            ((float4*)see)[threadIdx.x - PAIRS * 2] =
                ((const float4*)(eev + (size_t)c * PAIRS))[threadIdx.x - PAIRS * 2];
        }
    }

    const int n0 = blockIdx.x * (256 * PPT) + threadIdx.x;

    v2f zv[PPT][4], zzv[PPT];
    #pragma unroll
    for (int p = 0; p < PPT; ++p) {
        int n = n0 + p * 256;
        int b = n >> 12, hw = n & 4095;
        const float* zp = z + b * 16384 + hw;
        float a0 = zp[0], a1 = zp[CSTRIDE], a2 = zp[2 * CSTRIDE], a3 = zp[3 * CSTRIDE];
        float zz = __fmul_rn(a0, a0);
        zz = __fadd_rn(zz, __fmul_rn(a1, a1));
        zz = __fadd_rn(zz, __fmul_rn(a2, a2));
        zz = __fadd_rn(zz, __fmul_rn(a3, a3));
        zv[p][0] = (v2f){a0, a0}; zv[p][1] = (v2f){a1, a1};
        zv[p][2] = (v2f){a2, a2}; zv[p][3] = (v2f){a3, a3};
        zzv[p] = (v2f){zz, zz};
    }
    const v2f m2v = {-2.0f, -2.0f};

    __syncthreads();

    float run[PPT];
    #pragma unroll
    for (int p = 0; p < PPT; ++p) run[p] = __builtin_inff();

    const float4* sE4 = (const float4*)sE;
    #pragma unroll 4
    for (int t = 0; t < PAIRS; ++t) {
        // uniform LDS reads -> hardware broadcast, no bank conflicts
        float4 E01 = sE4[2 * t];       // {e0.lo,e0.hi, e1.lo,e1.hi}
        float4 E23 = sE4[2 * t + 1];   // {e2.lo,e2.hi, e3.lo,e3.hi}
        v2f ee2 = see[t];
        v2f e0 = {E01.x, E01.y};
        v2f e1 = {E01.z, E01.w};
        v2f e2 = {E23.x, E23.y};
        v2f e3 = {E23.z, E23.w};
        #pragma unroll
        for (int p = 0; p < PPT; ++p) {
            // per-half arithmetic identical to the scalar reference chain:
            v2f szz = pk_add(zzv[p], ee2);        // zz + ee_j         (rn)
            v2f dot = pk_mul(zv[p][0], e0);       // z0*e0             (rn)
            dot = pk_fma(zv[p][1], e1, dot);      // ascending-k fma chain
            dot = pk_fma(zv[p][2], e2, dot);
            dot = pk_fma(zv[p][3], e3, dot);
            v2f d2 = pk_fma(m2v, dot, szz);       // (zz+ee) - 2*dot (2*dot exact)
            run[p] = fminf(fminf(d2.x, d2.y), run[p]);   // exact selection (v_min3)
        }
    }

    #pragma unroll
    for (int p = 0; p < PPT; ++p)
        dmin[(size_t)c * N_POINTS + n0 + p * 256] = run[p];   // coalesced 256B/wave
}

// ---------------- kernel C (resolve): one WAVE per point; LDS transpose of dmin tile.
// gmin = min of 64 chunk-mins; FIRST chunk with cm==gmin holds the smallest index
// achieving gmin (chunks partition indices in order). Re-evaluate that chunk's 64
// pairs with the IDENTICAL pk chain (1 pair/lane) -> bitwise match guaranteed;
// min-reduce index among d==gmin (x-half checked last = smaller index priority).
__global__ __launch_bounds__(RB) void vq_resolve_kernel(
        const float* __restrict__ z, const float4* __restrict__ E,
        const v2f* __restrict__ Epk, const v2f* __restrict__ eev,
        const float* __restrict__ dmin,
        float* __restrict__ out, double* __restrict__ partial) {
    __shared__ float sCm[CH][9];                 // +1 pad: conflict-free transposed read
    __shared__ double sdata[RB / 64];
    const int lane = threadIdx.x & 63;
    const int wid = threadIdx.x >> 6;
    const int n0 = blockIdx.x * (RB / 64);
    const int n = n0 + wid;

    // ---- phase 1: cooperative tile load (1 float/thread)
    {
        int t = threadIdx.x;
        sCm[t >> 3][t & 7] = dmin[(size_t)(t >> 3) * N_POINTS + n0 + (t & 7)];
    }

    const int b = n >> 12;
    const int hw = n & 4095;
    const float* zp = z + b * 16384 + hw;
    float z0 = zp[0];
    float z1 = zp[CSTRIDE];
    float z2 = zp[2 * CSTRIDE];
    float z3 = zp[3 * CSTRIDE];
    float zz = __fmul_rn(z0, z0);
    zz = __fadd_rn(zz, __fmul_rn(z1, z1));
    zz = __fadd_rn(zz, __fmul_rn(z2, z2));
    zz = __fadd_rn(zz, __fmul_rn(z3, z3));

    __syncthreads();

    // lane c holds chunk c's min-d; wave min-reduce
    float cm = sCm[lane][wid];
    float gmin = cm;
    #pragma unroll
    for (int off = 32; off; off >>= 1)
        gmin = fminf(gmin, __shfl_xor(gmin, off));

    unsigned long long mask = __ballot(cm == gmin);   // >=1 bit; wave-uniform
    int cstar = __builtin_ctzll(mask);                // first chunk achieving gmin

    // re-evaluate chunk cstar: lane handles pair p (64 pairs = 1 chunk)
    int p = cstar * PAIRS + lane;
    const v2f* ep = Epk + (size_t)p * 4;
    v2f e0 = ep[0], e1 = ep[1], e2 = ep[2], e3 = ep[3];
    v2f ee2 = eev[p];
    v2f z0v = {z0, z0}, z1v = {z1, z1}, z2v = {z2, z2}, z3v = {z3, z3};
    v2f zzv = {zz, zz};
    v2f m2v = {-2.0f, -2.0f};
    v2f szz = pk_add(zzv, ee2);
    v2f dot = pk_mul(z0v, e0);
    dot = pk_fma(z1v, e1, dot);
    dot = pk_fma(z2v, e2, dot);
    dot = pk_fma(z3v, e3, dot);
    v2f d2 = pk_fma(m2v, dot, szz);       // bitwise == filter's values (same op, same inputs)

    int cand = 0x7FFFFFFF;
    if (d2.y == gmin) cand = 2 * p + 1;
    if (d2.x == gmin) cand = 2 * p;       // checked last: lo half (smaller j) wins
    #pragma unroll
    for (int off = 32; off; off >>= 1) {
        int o = __shfl_xor(cand, off);
        cand = o < cand ? o : cand;
    }
    int besti = cand;                     // guaranteed found: chunk contains gmin

    if (lane == 0) {
        float4 e = E[besti];
        float* op = out + b * 16384 + hw;
        float t0 = __fsub_rn(e.x, z0);
        float t1 = __fsub_rn(e.y, z1);
        float t2 = __fsub_rn(e.z, z2);
        float t3 = __fsub_rn(e.w, z3);
        op[0]           = __fadd_rn(z0, t0);     // straight-through: z + (z_q - z)
        op[CSTRIDE]     = __fadd_rn(z1, t1);
        op[2 * CSTRIDE] = __fadd_rn(z2, t2);
        op[3 * CSTRIDE] = __fadd_rn(z3, t3);
        out[131073 + n] = (float)besti;          // indices as float32 (exact)
        double ds = (double)__fmul_rn(t0, t0) + (double)__fmul_rn(t1, t1)
                  + (double)__fmul_rn(t2, t2) + (double)__fmul_rn(t3, t3);
        sdata[wid] = ds;
    }
    __syncthreads();
    if (threadIdx.x == 0) {
        double s = 0.0;
        #pragma unroll
        for (int w = 0; w < RB / 64; ++w) s += sdata[w];
        partial[blockIdx.x] = s;
    }
}

// ---------------- kernel D: deterministic loss reduce (4096 partials)
__global__ void vq_loss_kernel(const double* __restrict__ partial, float* __restrict__ out) {
    __shared__ double sdata[256];
    int t = threadIdx.x;
    double s = 0.0;
    for (int i = t; i < 4096; i += 256) s += partial[i];
    sdata[t] = s;
    __syncthreads();
    #pragma unroll
    for (int st = 128; st > 0; st >>= 1) {
        if (t < st) sdata[t] += sdata[t + st];
        __syncthreads();
    }
    if (t == 0) {
        float m = (float)(sdata[0] / 131072.0);
        // loss = mean + BETA*mean (both means are numerically identical)
        out[131072] = __fadd_rn(m, __fmul_rn(0.25f, m));
    }
}

extern "C" void kernel_launch(void* const* d_in, const int* in_sizes, int n_in,
                              void* d_out, int out_size, void* d_ws, size_t ws_size,
                              hipStream_t stream) {
    const float* z = (const float*)d_in[0];
    const float4* E = (const float4*)d_in[1];
    float* out = (float*)d_out;

    char* ws = (char*)d_ws;
    v2f* Epk = (v2f*)ws;                                      // 128 KB
    v2f* eev = (v2f*)(ws + 131072);                           // 32 KB
    float* dminb = (float*)(ws + 163840);                     // 8 MB, [c][n]
    double* partial = (double*)(ws + 163840 + (size_t)CH * N_POINTS * 4);  // 32 KB

    vq_prep_kernel<<<NPAIRS / 256, 256, 0, stream>>>(E, Epk, eev);
    vq_filter_kernel<<<dim3(N_POINTS / (256 * PPT), CH), 256, 0, stream>>>(z, Epk, eev, dminb);
    vq_resolve_kernel<<<N_POINTS / (RB / 64), RB, 0, stream>>>(z, E, Epk, eev, dminb, out, partial);
    vq_loss_kernel<<<1, 256, 0, stream>>>(partial, out);
}

// Round 15
// 62.730 us; speedup vs baseline: 1.0194x; 1.0194x over previous
//
#include <hip/hip_runtime.h>
#include <math.h>

typedef float v2f __attribute__((ext_vector_type(2)));

#define N_POINTS 32768
#define NUM_EMBED 8192
#define NPAIRS 4096
#define CH 64                                // chunks (64 chunk-mins fit one wave)
#define CPC (NUM_EMBED / CH)                 // 128 candidates per chunk
#define PAIRS (NPAIRS / CH)                  // 64 pairs per chunk (1 per lane in resolve)
#define PPT 4                                // filter points per thread -> 2048 blocks (8/CU)
#define RB 512                               // resolve block threads (8 waves, 8 points)
#define CSTRIDE 4096                         // 64*64, channel stride in z [B,C,H,W]

// ---------------- kernel A: build pair-interleaved codebook + ee (exact XLA arithmetic)
__global__ void vq_prep_kernel(const float4* __restrict__ E,
                               v2f* __restrict__ Epk, v2f* __restrict__ eev) {
    int p = blockIdx.x * 256 + threadIdx.x;
    if (p < NPAIRS) {
        float4 a = E[2 * p];
        float4 b = E[2 * p + 1];
        Epk[4 * p + 0] = (v2f){a.x, b.x};
        Epk[4 * p + 1] = (v2f){a.y, b.y};
        Epk[4 * p + 2] = (v2f){a.z, b.z};
        Epk[4 * p + 3] = (v2f){a.w, b.w};
        float ea = __fmul_rn(a.x, a.x);
        ea = __fadd_rn(ea, __fmul_rn(a.y, a.y));
        ea = __fadd_rn(ea, __fmul_rn(a.z, a.z));
        ea = __fadd_rn(ea, __fmul_rn(a.w, a.w));
        float eb = __fmul_rn(b.x, b.x);
        eb = __fadd_rn(eb, __fmul_rn(b.y, b.y));
        eb = __fadd_rn(eb, __fmul_rn(b.z, b.z));
        eb = __fadd_rn(eb, __fmul_rn(b.w, b.w));
        eev[p] = (v2f){ea, eb};
    }
}

// packed f32 ops forced via inline asm (per-half IEEE rn; deterministic)
__device__ __forceinline__ v2f pk_add(v2f a, v2f b) {
    v2f d; asm("v_pk_add_f32 %0, %1, %2" : "=v"(d) : "v"(a), "v"(b)); return d;
}
__device__ __forceinline__ v2f pk_mul(v2f a, v2f b) {
    v2f d; asm("v_pk_mul_f32 %0, %1, %2" : "=v"(d) : "v"(a), "v"(b)); return d;
}
__device__ __forceinline__ v2f pk_fma(v2f a, v2f b, v2f c) {
    v2f d; asm("v_pk_fma_f32 %0, %1, %2, %3" : "=v"(d) : "v"(a), "v"(b), "v"(c)); return d;
}

// ---------------- kernel B (filter): per (point, chunk) EXACT min of d (value only)
// d chain = the proven bit-exact reference chain (r8): szz=zz+ee; mul+fma dot; fma(-2,...)
__global__ __launch_bounds__(256, 1) void vq_filter_kernel(
        const float* __restrict__ z, const v2f* __restrict__ Epk,
        const v2f* __restrict__ eev, float* __restrict__ dmin) {
    __shared__ alignas(16) v2f sE[PAIRS * 4];   // 2 KB
    __shared__ alignas(16) v2f see[PAIRS];      // 512 B

    const int c = blockIdx.y;
    {
        const float4* gE = (const float4*)(Epk + (size_t)c * PAIRS * 4);
        if (threadIdx.x < PAIRS * 2) {
            ((float4*)sE)[threadIdx.x] = gE[threadIdx.x];
        } else if (threadIdx.x < PAIRS * 2 + PAIRS / 2) {
            ((float4*)see)[threadIdx.x - PAIRS * 2] =
                ((const float4*)(eev + (size_t)c * PAIRS))[threadIdx.x - PAIRS * 2];
        }
    }

    const int n0 = blockIdx.x * (256 * PPT) + threadIdx.x;

    v2f zv[PPT][4], zzv[PPT];
    #pragma unroll
    for (int p = 0; p < PPT; ++p) {
        int n = n0 + p * 256;
        int b = n >> 12, hw = n & 4095;
        const float* zp = z + b * 16384 + hw;
        float a0 = zp[0], a1 = zp[CSTRIDE], a2 = zp[2 * CSTRIDE], a3 = zp[3 * CSTRIDE];
        float zz = __fmul_rn(a0, a0);
        zz = __fadd_rn(zz, __fmul_rn(a1, a1));
        zz = __fadd_rn(zz, __fmul_rn(a2, a2));
        zz = __fadd_rn(zz, __fmul_rn(a3, a3));
        zv[p][0] = (v2f){a0, a0}; zv[p][1] = (v2f){a1, a1};
        zv[p][2] = (v2f){a2, a2}; zv[p][3] = (v2f){a3, a3};
        zzv[p] = (v2f){zz, zz};
    }
    const v2f m2v = {-2.0f, -2.0f};

    __syncthreads();

    float run[PPT];
    #pragma unroll
    for (int p = 0; p < PPT; ++p) run[p] = __builtin_inff();

    const float4* sE4 = (const float4*)sE;
    #pragma unroll 4
    for (int t = 0; t < PAIRS; ++t) {
        // uniform LDS reads -> hardware broadcast, no bank conflicts
        float4 E01 = sE4[2 * t];       // {e0.lo,e0.hi, e1.lo,e1.hi}
        float4 E23 = sE4[2 * t + 1];   // {e2.lo,e2.hi, e3.lo,e3.hi}
        v2f ee2 = see[t];
        v2f e0 = {E01.x, E01.y};
        v2f e1 = {E01.z, E01.w};
        v2f e2 = {E23.x, E23.y};
        v2f e3 = {E23.z, E23.w};
        #pragma unroll
        for (int p = 0; p < PPT; ++p) {
            // per-half arithmetic identical to the scalar reference chain:
            v2f szz = pk_add(zzv[p], ee2);        // zz + ee_j         (rn)
            v2f dot = pk_mul(zv[p][0], e0);       // z0*e0             (rn)
            dot = pk_fma(zv[p][1], e1, dot);      // ascending-k fma chain
            dot = pk_fma(zv[p][2], e2, dot);
            dot = pk_fma(zv[p][3], e3, dot);
            v2f d2 = pk_fma(m2v, dot, szz);       // (zz+ee) - 2*dot (2*dot exact)
            run[p] = fminf(fminf(d2.x, d2.y), run[p]);   // exact selection (v_min3)
        }
    }

    #pragma unroll
    for (int p = 0; p < PPT; ++p)
        dmin[(size_t)c * N_POINTS + n0 + p * 256] = run[p];   // coalesced 256B/wave
}

// ---------------- kernel C (resolve): one WAVE per point; LDS transpose of dmin tile.
// gmin = min of 64 chunk-mins; FIRST chunk with cm==gmin holds the smallest index
// achieving gmin (chunks partition indices in order). Re-evaluate that chunk's 64
// pairs with the IDENTICAL pk chain (1 pair/lane) -> bitwise match guaranteed;
// min-reduce index among d==gmin (x-half checked last = smaller index priority).
__global__ __launch_bounds__(RB) void vq_resolve_kernel(
        const float* __restrict__ z, const float4* __restrict__ E,
        const v2f* __restrict__ Epk, const v2f* __restrict__ eev,
        const float* __restrict__ dmin,
        float* __restrict__ out, double* __restrict__ partial) {
    __shared__ float sCm[CH][9];                 // +1 pad: conflict-free transposed read
    __shared__ double sdata[RB / 64];
    const int lane = threadIdx.x & 63;
    const int wid = threadIdx.x >> 6;
    const int n0 = blockIdx.x * (RB / 64);
    const int n = n0 + wid;

    // ---- phase 1: cooperative tile load (1 float/thread)
    {
        int t = threadIdx.x;
        sCm[t >> 3][t & 7] = dmin[(size_t)(t >> 3) * N_POINTS + n0 + (t & 7)];
    }

    const int b = n >> 12;
    const int hw = n & 4095;
    const float* zp = z + b * 16384 + hw;
    float z0 = zp[0];
    float z1 = zp[CSTRIDE];
    float z2 = zp[2 * CSTRIDE];
    float z3 = zp[3 * CSTRIDE];
    float zz = __fmul_rn(z0, z0);
    zz = __fadd_rn(zz, __fmul_rn(z1, z1));
    zz = __fadd_rn(zz, __fmul_rn(z2, z2));
    zz = __fadd_rn(zz, __fmul_rn(z3, z3));

    __syncthreads();

    // lane c holds chunk c's min-d; wave min-reduce
    float cm = sCm[lane][wid];
    float gmin = cm;
    #pragma unroll
    for (int off = 32; off; off >>= 1)
        gmin = fminf(gmin, __shfl_xor(gmin, off));

    unsigned long long mask = __ballot(cm == gmin);   // >=1 bit; wave-uniform
    int cstar = __builtin_ctzll(mask);                // first chunk achieving gmin

    // re-evaluate chunk cstar: lane handles pair p (64 pairs = 1 chunk)
    int p = cstar * PAIRS + lane;
    const v2f* ep = Epk + (size_t)p * 4;
    v2f e0 = ep[0], e1 = ep[1], e2 = ep[2], e3 = ep[3];
    v2f ee2 = eev[p];
    v2f z0v = {z0, z0}, z1v = {z1, z1}, z2v = {z2, z2}, z3v = {z3, z3};
    v2f zzv = {zz, zz};
    v2f m2v = {-2.0f, -2.0f};
    v2f szz = pk_add(zzv, ee2);
    v2f dot = pk_mul(z0v, e0);
    dot = pk_fma(z1v, e1, dot);
    dot = pk_fma(z2v, e2, dot);
    dot = pk_fma(z3v, e3, dot);
    v2f d2 = pk_fma(m2v, dot, szz);       // bitwise == filter's values (same op, same inputs)

    int cand = 0x7FFFFFFF;
    if (d2.y == gmin) cand = 2 * p + 1;
    if (d2.x == gmin) cand = 2 * p;       // checked last: lo half (smaller j) wins
    #pragma unroll
    for (int off = 32; off; off >>= 1) {
        int o = __shfl_xor(cand, off);
        cand = o < cand ? o : cand;
    }
    int besti = cand;                     // guaranteed found: chunk contains gmin

    if (lane == 0) {
        float4 e = E[besti];
        float* op = out + b * 16384 + hw;
        float t0 = __fsub_rn(e.x, z0);
        float t1 = __fsub_rn(e.y, z1);
        float t2 = __fsub_rn(e.z, z2);
        float t3 = __fsub_rn(e.w, z3);
        op[0]           = __fadd_rn(z0, t0);     // straight-through: z + (z_q - z)
        op[CSTRIDE]     = __fadd_rn(z1, t1);
        op[2 * CSTRIDE] = __fadd_rn(z2, t2);
        op[3 * CSTRIDE] = __fadd_rn(z3, t3);
        out[131073 + n] = (float)besti;          // indices as float32 (exact)
        double ds = (double)__fmul_rn(t0, t0) + (double)__fmul_rn(t1, t1)
                  + (double)__fmul_rn(t2, t2) + (double)__fmul_rn(t3, t3);
        sdata[wid] = ds;
    }
    __syncthreads();
    if (threadIdx.x == 0) {
        double s = 0.0;
        #pragma unroll
        for (int w = 0; w < RB / 64; ++w) s += sdata[w];
        partial[blockIdx.x] = s;
    }
}

// ---------------- kernel D: deterministic loss reduce (4096 partials)
__global__ void vq_loss_kernel(const double* __restrict__ partial, float* __restrict__ out) {
    __shared__ double sdata[256];
    int t = threadIdx.x;
    double s = 0.0;
    for (int i = t; i < 4096; i += 256) s += partial[i];
    sdata[t] = s;
    __syncthreads();
    #pragma unroll
    for (int st = 128; st > 0; st >>= 1) {
        if (t < st) sdata[t] += sdata[t + st];
        __syncthreads();
    }
    if (t == 0) {
        float m = (float)(sdata[0] / 131072.0);
        // loss = mean + BETA*mean (both means are numerically identical)
        out[131072] = __fadd_rn(m, __fmul_rn(0.25f, m));
    }
}

extern "C" void kernel_launch(void* const* d_in, const int* in_sizes, int n_in,
                              void* d_out, int out_size, void* d_ws, size_t ws_size,
                              hipStream_t stream) {
    const float* z = (const float*)d_in[0];
    const float4* E = (const float4*)d_in[1];
    float* out = (float*)d_out;

    char* ws = (char*)d_ws;
    v2f* Epk = (v2f*)ws;                                      // 128 KB
    v2f* eev = (v2f*)(ws + 131072);                           // 32 KB
    float* dminb = (float*)(ws + 163840);                     // 8 MB, [c][n]
    double* partial = (double*)(ws + 163840 + (size_t)CH * N_POINTS * 4);  // 32 KB

    vq_prep_kernel<<<NPAIRS / 256, 256, 0, stream>>>(E, Epk, eev);
    vq_filter_kernel<<<dim3(N_POINTS / (256 * PPT), CH), 256, 0, stream>>>(z, Epk, eev, dminb);
    vq_resolve_kernel<<<N_POINTS / (RB / 64), RB, 0, stream>>>(z, E, Epk, eev, dminb, out, partial);
    vq_loss_kernel<<<1, 256, 0, stream>>>(partial, out);
}

// Round 16
// 53.026 us; speedup vs baseline: 1.2059x; 1.1830x over previous
//
#include <hip/hip_runtime.h>
#include <math.h>

typedef float v2f __attribute__((ext_vector_type(2)));

#define N_POINTS 32768
#define NUM_EMBED 8192
#define NPAIRS 4096
#define CH 64                                // chunks (fits 64-bit survivor mask)
#define CPC (NUM_EMBED / CH)                 // 128 candidates per chunk
#define PAIRS (NPAIRS / CH)                  // 64 pairs per chunk
#define PPT 4                                // filter points per thread (r9-proven shape)
#define RB 1024                              // resolve block threads (16 waves, 16 points)
#define RPB (RB / 64)                        // 16 points per resolve block
#define CSTRIDE 4096                         // 64*64, channel stride in z [B,C,H,W]

// ---------------- kernel A: build pair-interleaved codebook (bits preserved)
__global__ void vq_prep_kernel(const float4* __restrict__ E, v2f* __restrict__ Epk) {
    int p = blockIdx.x * 256 + threadIdx.x;
    if (p < NPAIRS) {
        float4 a = E[2 * p];
        float4 b = E[2 * p + 1];
        Epk[4 * p + 0] = (v2f){a.x, b.x};
        Epk[4 * p + 1] = (v2f){a.y, b.y};
        Epk[4 * p + 2] = (v2f){a.z, b.z};
        Epk[4 * p + 3] = (v2f){a.w, b.w};
    }
}

// packed f32 ops forced via inline asm (per-half IEEE rn, bit-identical to scalar chain)
__device__ __forceinline__ v2f pk_mul(v2f a, v2f b) {
    v2f d; asm("v_pk_mul_f32 %0, %1, %2" : "=v"(d) : "v"(a), "v"(b)); return d;
}
__device__ __forceinline__ v2f pk_fma(v2f a, v2f b, v2f c) {
    v2f d; asm("v_pk_fma_f32 %0, %1, %2, %3" : "=v"(d) : "v"(a), "v"(b), "v"(c)); return d;
}

// order-preserving bijection float -> uint32 (total order == float <)
__device__ __forceinline__ unsigned int fkey(float f) {
    unsigned int b = __float_as_uint(f);
    return b ^ (0x80000000u | (unsigned int)((int)b >> 31));
}

// ---------------- kernel B (filter): per (point, chunk) max of dot_j (r9-proven, ~floor)
// dot chain = exact XLA chain bits (mul + ascending fma) -> fmax selection is exact.
__global__ __launch_bounds__(256) void vq_filter_kernel(
        const float* __restrict__ z, const v2f* __restrict__ Epk,
        float* __restrict__ cmax) {
    __shared__ alignas(16) v2f sE[PAIRS * 4];   // 2 KB

    const int c = blockIdx.y;
    if (threadIdx.x < PAIRS * 2) {
        ((float4*)sE)[threadIdx.x] =
            ((const float4*)(Epk + (size_t)c * PAIRS * 4))[threadIdx.x];
    }

    const int n0 = blockIdx.x * (256 * PPT) + threadIdx.x;

    v2f zv[PPT][4];
    #pragma unroll
    for (int p = 0; p < PPT; ++p) {
        int n = n0 + p * 256;
        int b = n >> 12, hw = n & 4095;
        const float* zp = z + b * 16384 + hw;
        zv[p][0] = (v2f){zp[0], zp[0]};
        zv[p][1] = (v2f){zp[CSTRIDE], zp[CSTRIDE]};
        zv[p][2] = (v2f){zp[2 * CSTRIDE], zp[2 * CSTRIDE]};
        zv[p][3] = (v2f){zp[3 * CSTRIDE], zp[3 * CSTRIDE]};
    }

    __syncthreads();

    float run[PPT];
    #pragma unroll
    for (int p = 0; p < PPT; ++p) run[p] = -__builtin_inff();

    const float4* sE4 = (const float4*)sE;
    #pragma unroll 4
    for (int t = 0; t < PAIRS; ++t) {
        // uniform LDS reads -> hardware broadcast, no bank conflicts
        float4 E01 = sE4[2 * t];       // {e0.lo,e0.hi, e1.lo,e1.hi}
        float4 E23 = sE4[2 * t + 1];   // {e2.lo,e2.hi, e3.lo,e3.hi}
        v2f e0 = {E01.x, E01.y};
        v2f e1 = {E01.z, E01.w};
        v2f e2 = {E23.x, E23.y};
        v2f e3 = {E23.z, E23.w};
        #pragma unroll
        for (int p = 0; p < PPT; ++p) {
            v2f dot = pk_mul(zv[p][0], e0);       // z0*e0       (rn)
            dot = pk_fma(zv[p][1], e1, dot);      // ascending-k fma chain
            dot = pk_fma(zv[p][2], e2, dot);
            dot = pk_fma(zv[p][3], e3, dot);
            run[p] = fmaxf(fmaxf(dot.x, dot.y), run[p]);  // exact selection (v_max3)
        }
    }

    #pragma unroll
    for (int p = 0; p < PPT; ++p)
        cmax[(size_t)c * N_POINTS + n0 + p * 256] = run[p];   // coalesced 256B/wave
}

// ---------------- kernel C (resolve): 16 waves / 16 points per block.
// Phase 1: 1024 threads load the block's [64c][16n] cmax tile as FULL 64B lines
// (thread t -> row t>>4, col t&15) into padded LDS. Phase 2 per wave (r11-proven):
// shfl-reduce gmax; conservative threshold; ballot -> survivor mask; coalesced
// exact rescan of survivors; 64-bit key min-reduce = exact first-index argmin.
__global__ __launch_bounds__(RB) void vq_resolve_kernel(
        const float* __restrict__ z, const float4* __restrict__ E,
        const float* __restrict__ cmax,
        float* __restrict__ out, double* __restrict__ partial) {
    __shared__ float sCm[CH][RPB + 1];           // 64 x 17 floats: odd stride, <=2-way
    __shared__ double sdata[RPB];
    const int lane = threadIdx.x & 63;
    const int wid = threadIdx.x >> 6;
    const int n0 = blockIdx.x * RPB;
    const int n = n0 + wid;

    // ---- phase 1: cooperative tile load, line-granular (64B per 16 threads)
    {
        int t = threadIdx.x;
        sCm[t >> 4][t & 15] = cmax[(size_t)(t >> 4) * N_POINTS + n0 + (t & 15)];
    }

    const int b = n >> 12;
    const int hw = n & 4095;
    const float* zp = z + b * 16384 + hw;
    float z0 = zp[0];
    float z1 = zp[CSTRIDE];
    float z2 = zp[2 * CSTRIDE];
    float z3 = zp[3 * CSTRIDE];
    float zz = __fmul_rn(z0, z0);
    zz = __fadd_rn(zz, __fmul_rn(z1, z1));
    zz = __fadd_rn(zz, __fmul_rn(z2, z2));
    zz = __fadd_rn(zz, __fmul_rn(z3, z3));

    __syncthreads();

    // lane c holds chunk c's max-dot; wave max-reduce
    float cm = sCm[lane][wid];
    float gmax = cm;
    #pragma unroll
    for (int off = 32; off; off >>= 1)
        gmax = fmaxf(gmax, __shfl_xor(gmax, off));

    // conservative bound (proven round 9): survivors have dot >= gmax - (2u + 1e-7)
    float u = __fmul_rn(__fadd_rn(zz, 0.01f), 2.38418579e-07f);   // (zz+.01)*2^-22
    float thr = __fsub_rn(gmax, __fadd_rn(__fadd_rn(u, u), 1e-7f));
    unsigned long long mask = __ballot(cm >= thr);   // wave-uniform, >=1 bit set

    // exact rescan of surviving chunks (coalesced: lane -> j0+lane, j0+64+lane)
    unsigned long long bkey = ~0ull;
    while (mask) {
        int c = __builtin_ctzll(mask);
        mask &= mask - 1ull;
        int j0 = c * CPC + lane;
        #pragma unroll
        for (int h = 0; h < 2; ++h) {
            int j = j0 + h * 64;
            float4 e = E[j];
            float ee = __fmul_rn(e.x, e.x);
            ee = __fadd_rn(ee, __fmul_rn(e.y, e.y));
            ee = __fadd_rn(ee, __fmul_rn(e.z, e.z));
            ee = __fadd_rn(ee, __fmul_rn(e.w, e.w));
            float dot = __fmul_rn(z0, e.x);
            dot = __fmaf_rn(z1, e.y, dot);
            dot = __fmaf_rn(z2, e.z, dot);
            dot = __fmaf_rn(z3, e.w, dot);
            float d = __fmaf_rn(-2.0f, dot, __fadd_rn(zz, ee));
            // key: (orderable d) << 32 | j  -> min key = min d, tie -> min j (first index)
            unsigned long long key =
                ((unsigned long long)fkey(d) << 32) | (unsigned int)j;
            bkey = key < bkey ? key : bkey;
        }
    }
    #pragma unroll
    for (int off = 32; off; off >>= 1) {
        unsigned long long o = __shfl_xor(bkey, off);
        bkey = o < bkey ? o : bkey;
    }
    int besti = (int)(unsigned int)(bkey & 0xFFFFFFFFull);

    if (lane == 0) {
        float4 e = E[besti];
        float* op = out + b * 16384 + hw;
        float t0 = __fsub_rn(e.x, z0);
        float t1 = __fsub_rn(e.y, z1);
        float t2 = __fsub_rn(e.z, z2);
        float t3 = __fsub_rn(e.w, z3);
        op[0]           = __fadd_rn(z0, t0);     // straight-through: z + (z_q - z)
        op[CSTRIDE]     = __fadd_rn(z1, t1);
        op[2 * CSTRIDE] = __fadd_rn(z2, t2);
        op[3 * CSTRIDE] = __fadd_rn(z3, t3);
        out[131073 + n] = (float)besti;          // indices as float32 (exact)
        double ds = (double)__fmul_rn(t0, t0) + (double)__fmul_rn(t1, t1)
                  + (double)__fmul_rn(t2, t2) + (double)__fmul_rn(t3, t3);
        sdata[wid] = ds;
    }
    __syncthreads();
    if (threadIdx.x == 0) {
        double s = 0.0;
        #pragma unroll
        for (int w = 0; w < RPB; ++w) s += sdata[w];
        partial[blockIdx.x] = s;
    }
}

// ---------------- kernel D: deterministic loss reduce (2048 partials)
__global__ void vq_loss_kernel(const double* __restrict__ partial, float* __restrict__ out) {
    __shared__ double sdata[256];
    int t = threadIdx.x;
    double s = 0.0;
    for (int i = t; i < 2048; i += 256) s += partial[i];
    sdata[t] = s;
    __syncthreads();
    #pragma unroll
    for (int st = 128; st > 0; st >>= 1) {
        if (t < st) sdata[t] += sdata[t + st];
        __syncthreads();
    }
    if (t == 0) {
        float m = (float)(sdata[0] / 131072.0);
        // loss = mean + BETA*mean (both means are numerically identical)
        out[131072] = __fadd_rn(m, __fmul_rn(0.25f, m));
    }
}

extern "C" void kernel_launch(void* const* d_in, const int* in_sizes, int n_in,
                              void* d_out, int out_size, void* d_ws, size_t ws_size,
                              hipStream_t stream) {
    const float* z = (const float*)d_in[0];
    const float4* E = (const float4*)d_in[1];
    float* out = (float*)d_out;

    char* ws = (char*)d_ws;
    v2f* Epk = (v2f*)ws;                                      // 128 KB
    float* cmaxb = (float*)(ws + 131072);                     // 8 MB, [c][n]
    double* partial = (double*)(ws + 131072 + (size_t)CH * N_POINTS * 4);  // 16 KB

    vq_prep_kernel<<<NPAIRS / 256, 256, 0, stream>>>(E, Epk);
    vq_filter_kernel<<<dim3(N_POINTS / (256 * PPT), CH), 256, 0, stream>>>(z, Epk, cmaxb);
    vq_resolve_kernel<<<N_POINTS / RPB, RB, 0, stream>>>(z, E, cmaxb, out, partial);
    vq_loss_kernel<<<1, 256, 0, stream>>>(partial, out);
}